// Round 12
// baseline (238.080 us; speedup 1.0000x reference)
//
#include <hip/hip_runtime.h>

#define BINS  256
#define NCOPY 8
#define BLOCK 512      // 8 waves: 0-3 ballot, 4-6 LDS-atomic, 7 global-atomic
#define GRID  1024     // 4 blocks/CU exactly (32 waves/CU)
#define GCOPY 32       // global histogram copies: 32*512*4B = 64KB in d_ws

#define NB 256         // ballot threads per block (waves 0-3)
#define ND 192         // DS threads per block (waves 4-6)
#define NG 64          // global-atomic threads per block (wave 7)

typedef unsigned int u32;
typedef unsigned long long u64;

// ---- DS pipe: fire-and-forget LDS atomic (~640 G values/s chip, calibrated) ----
__device__ __forceinline__ void dbin(float x, u32* hc) {
    if (x >= 0.0f && x <= 1.0f) {
        u32 bin = (u32)(x * 256.0f);     // trunc==floor for x>=0; matches JAX
        bin = bin > 255u ? 255u : bin;
        atomicAdd(&hc[bin * NCOPY], 1u);
    }
}

// ---- global pipe: fire-and-forget L2 atomic (rate = this round's experiment) ----
__device__ __forceinline__ void gbin_c(float x, u32* gc) {   // gc = copy base (+256 for img2)
    if (x >= 0.0f && x <= 1.0f) {
        u32 bin = (u32)(x * 256.0f);
        bin = bin > 255u ? 255u : bin;
        atomicAdd(&gc[bin], 1u);
    }
}

// ---- ballot pipe: bit-slice count (~400 G values/s, calibrated; asm front-end) ----
__device__ __forceinline__ void bs_round(float x, const u32 e[6], u32 cnt[4])
{
    u64 ge, le, b0, b1, b2, b3, b4, b5, b6, b7;
    u32 vb, t0, t1;
    asm("v_mul_f32 %[vb], 0x43800000, %[x]\n\t"
        "v_cvt_u32_f32 %[vb], %[vb]\n\t"
        "v_min_u32 %[vb], 0xff, %[vb]\n\t"
        "v_cmp_ge_f32 %[ge], %[x], 0\n\t"
        "v_cmp_le_f32 %[le], %[x], 1.0\n\t"
        "v_lshlrev_b32 %[t0], 31, %[vb]\n\t"
        "v_cmp_lt_i32 %[b0], %[t0], 0\n\t"
        "v_lshlrev_b32 %[t1], 30, %[vb]\n\t"
        "v_cmp_lt_i32 %[b1], %[t1], 0\n\t"
        "v_lshlrev_b32 %[t0], 29, %[vb]\n\t"
        "v_cmp_lt_i32 %[b2], %[t0], 0\n\t"
        "v_lshlrev_b32 %[t1], 28, %[vb]\n\t"
        "v_cmp_lt_i32 %[b3], %[t1], 0\n\t"
        "v_lshlrev_b32 %[t0], 27, %[vb]\n\t"
        "v_cmp_lt_i32 %[b4], %[t0], 0\n\t"
        "v_lshlrev_b32 %[t1], 26, %[vb]\n\t"
        "v_cmp_lt_i32 %[b5], %[t1], 0\n\t"
        "v_lshlrev_b32 %[t0], 25, %[vb]\n\t"
        "v_cmp_lt_i32 %[b6], %[t0], 0\n\t"
        "v_lshlrev_b32 %[t1], 24, %[vb]\n\t"
        "v_cmp_lt_i32 %[b7], %[t1], 0"
        : [ge] "=&s"(ge), [le] "=&s"(le),
          [b0] "=&s"(b0), [b1] "=&s"(b1), [b2] "=&s"(b2), [b3] "=&s"(b3),
          [b4] "=&s"(b4), [b5] "=&s"(b5), [b6] "=&s"(b6), [b7] "=&s"(b7),
          [vb] "=&v"(vb), [t0] "=&v"(t0), [t1] "=&v"(t1)
        : [x] "v"(x));

    const u64 mv = ge & le;

    u32 aLo = (u32)mv
            & (((u32)b2) ^ e[0]) & (((u32)b3) ^ e[1]) & (((u32)b4) ^ e[2])
            & (((u32)b5) ^ e[3]) & (((u32)b6) ^ e[4]) & (((u32)b7) ^ e[5]);
    u32 aHi = (u32)(mv >> 32)
            & (((u32)(b2 >> 32)) ^ e[0]) & (((u32)(b3 >> 32)) ^ e[1])
            & (((u32)(b4 >> 32)) ^ e[2]) & (((u32)(b5 >> 32)) ^ e[3])
            & (((u32)(b6 >> 32)) ^ e[4]) & (((u32)(b7 >> 32)) ^ e[5]);

    const u64 c00 = ~(b0 | b1);
    const u64 c01 = b0 & ~b1;
    const u64 c10 = ~b0 & b1;
    const u64 c11 = b0 & b1;
    cnt[0] += __popc(aLo & (u32)c00) + __popc(aHi & (u32)(c00 >> 32));
    cnt[1] += __popc(aLo & (u32)c01) + __popc(aHi & (u32)(c01 >> 32));
    cnt[2] += __popc(aLo & (u32)c10) + __popc(aHi & (u32)(c10 >> 32));
    cnt[3] += __popc(aLo & (u32)c11) + __popc(aHi & (u32)(c11 >> 32));
}

__device__ __forceinline__ void bs4(float4 v, const u32 e[6], u32 cnt[4])
{
    bs_round(v.x, e, cnt);
    bs_round(v.y, e, cnt);
    bs_round(v.z, e, cnt);
    bs_round(v.w, e, cnt);
}

// Three-pipe wave-role kernel: ballot (VALU) / LDS-atomic (DS unit) / global-atomic (TCC).
__global__ __launch_bounds__(BLOCK, 8) void hist_kernel(
    const float* __restrict__ img1, const float* __restrict__ img2,
    u32* __restrict__ g_h1, u32* __restrict__ g_h2,
    u32* __restrict__ gcop,       // GCOPY x [2][256] global copies (may be unused)
    int g_on, long long n)
{
    __shared__ u32 lh[2][BINS][NCOPY];       // 16 KB, bank-spread copies

    const int tid  = threadIdx.x;
    const int lane = tid & 63;
    const int copy = tid & (NCOPY - 1);

    for (int k = tid; k < 2 * BINS * NCOPY; k += BLOCK)
        ((u32*)lh)[k] = 0u;
    __syncthreads();

    u32 cnt1[4] = {0u, 0u, 0u, 0u};
    u32 cnt2[4] = {0u, 0u, 0u, 0u};
    u32* h1c = &lh[0][0][copy];
    u32* h2c = &lh[1][0][copy];

    const long long n4 = n >> 2;
    const long long unit = (long long)GRID * NG;       // 65536 quads
    const long long units = n4 / unit;
    const long long tripsB = units / 12;               // ballot: 4 units/trip -> ~1/3 of values
    long long tripsD, tripsG;
    if (g_on) {
        tripsD = (units * 3) / 16;                     // DS: 3 units/trip -> ~56%
        tripsG = units - 4 * tripsB - 3 * tripsD;      // global absorbs the rest (~10%)
    } else {
        tripsD = (units - 4 * tripsB) / 3;
        tripsG = 0;
    }
    const long long S_b = (long long)GRID * NB;
    const long long S_d = (long long)GRID * ND;
    const long long S_g = (long long)GRID * NG;
    const long long QB = tripsB * S_b;                 // ballot quads   [0, QB)
    const long long QD = QB + tripsD * S_d;            // DS quads       [QB, QD)
    const long long covered = QD + tripsG * S_g;       // global quads   [QD, covered)

    const float4* p1 = (const float4*)img1;
    const float4* p2 = (const float4*)img2;

    if (tid < NB) {
        // ---- ballot role (waves 0-3, one per SIMD) ----
        u32 e[6];
#pragma unroll
        for (int k = 0; k < 6; ++k)
            e[k] = ((lane >> k) & 1) ? 0u : 0xFFFFFFFFu;

        long long i = (long long)blockIdx.x * NB + tid;
        if (tripsB >= 2) {
            float4 a0 = p1[i],  b0 = p2[i];
            long long ii = i + S_b;
            float4 a1 = p1[ii], b1 = p2[ii];
            for (long long t = 0; t + 2 < tripsB; ++t) {
                const long long in = ii + S_b;
                float4 a2 = p1[in], b2v = p2[in];
                bs4(a0, e, cnt1); bs4(b0, e, cnt2);
                a0 = a1; b0 = b1; a1 = a2; b1 = b2v; ii = in;
            }
            bs4(a0, e, cnt1); bs4(b0, e, cnt2);
            bs4(a1, e, cnt1); bs4(b1, e, cnt2);
        } else if (tripsB == 1) {
            float4 a0 = p1[i], b0 = p2[i];
            bs4(a0, e, cnt1); bs4(b0, e, cnt2);
        }
    } else if (tid < NB + ND) {
        // ---- DS role (waves 4-6): fire-and-forget LDS atomics ----
        long long i = QB + (long long)blockIdx.x * ND + (tid - NB);
        if (tripsD >= 2) {
            float4 a0 = p1[i],  b0 = p2[i];
            long long ii = i + S_d;
            float4 a1 = p1[ii], b1 = p2[ii];
            for (long long t = 0; t + 2 < tripsD; ++t) {
                const long long in = ii + S_d;
                float4 a2 = p1[in], b2v = p2[in];
                dbin(a0.x, h1c); dbin(a0.y, h1c); dbin(a0.z, h1c); dbin(a0.w, h1c);
                dbin(b0.x, h2c); dbin(b0.y, h2c); dbin(b0.z, h2c); dbin(b0.w, h2c);
                a0 = a1; b0 = b1; a1 = a2; b1 = b2v; ii = in;
            }
            dbin(a0.x, h1c); dbin(a0.y, h1c); dbin(a0.z, h1c); dbin(a0.w, h1c);
            dbin(b0.x, h2c); dbin(b0.y, h2c); dbin(b0.z, h2c); dbin(b0.w, h2c);
            dbin(a1.x, h1c); dbin(a1.y, h1c); dbin(a1.z, h1c); dbin(a1.w, h1c);
            dbin(b1.x, h2c); dbin(b1.y, h2c); dbin(b1.z, h2c); dbin(b1.w, h2c);
        } else if (tripsD == 1) {
            float4 a0 = p1[i], b0 = p2[i];
            dbin(a0.x, h1c); dbin(a0.y, h1c); dbin(a0.z, h1c); dbin(a0.w, h1c);
            dbin(b0.x, h2c); dbin(b0.y, h2c); dbin(b0.z, h2c); dbin(b0.w, h2c);
        }
    } else if (tripsG > 0) {
        // ---- global role (wave 7): fire-and-forget L2 atomics, spread copies ----
        u32* gc1 = gcop + (u32)(lane & (GCOPY - 1)) * 512u;   // [copy][img][bin]
        u32* gc2 = gc1 + 256;
        long long i = QD + (long long)blockIdx.x * NG + (tid - NB - ND);
        if (tripsG >= 2) {
            float4 a0 = p1[i],  b0 = p2[i];
            long long ii = i + S_g;
            float4 a1 = p1[ii], b1 = p2[ii];
            for (long long t = 0; t + 2 < tripsG; ++t) {
                const long long in = ii + S_g;
                float4 a2 = p1[in], b2v = p2[in];
                gbin_c(a0.x, gc1); gbin_c(a0.y, gc1); gbin_c(a0.z, gc1); gbin_c(a0.w, gc1);
                gbin_c(b0.x, gc2); gbin_c(b0.y, gc2); gbin_c(b0.z, gc2); gbin_c(b0.w, gc2);
                a0 = a1; b0 = b1; a1 = a2; b1 = b2v; ii = in;
            }
            gbin_c(a0.x, gc1); gbin_c(a0.y, gc1); gbin_c(a0.z, gc1); gbin_c(a0.w, gc1);
            gbin_c(b0.x, gc2); gbin_c(b0.y, gc2); gbin_c(b0.z, gc2); gbin_c(b0.w, gc2);
            gbin_c(a1.x, gc1); gbin_c(a1.y, gc1); gbin_c(a1.z, gc1); gbin_c(a1.w, gc1);
            gbin_c(b1.x, gc2); gbin_c(b1.y, gc2); gbin_c(b1.z, gc2); gbin_c(b1.w, gc2);
        } else {
            float4 a0 = p1[i], b0 = p2[i];
            gbin_c(a0.x, gc1); gbin_c(a0.y, gc1); gbin_c(a0.z, gc1); gbin_c(a0.w, gc1);
            gbin_c(b0.x, gc2); gbin_c(b0.y, gc2); gbin_c(b0.z, gc2); gbin_c(b0.w, gc2);
        }
    }

    // generic tails -> LDS pipe (empty for this shape)
    {
        const long long gtid = (long long)blockIdx.x * BLOCK + tid;
        const long long nthr = (long long)GRID * BLOCK;
        for (long long q = covered + gtid; q < n4; q += nthr) {
            float4 a = p1[q], b = p2[q];
            dbin(a.x, h1c); dbin(a.y, h1c); dbin(a.z, h1c); dbin(a.w, h1c);
            dbin(b.x, h2c); dbin(b.y, h2c); dbin(b.z, h2c); dbin(b.w, h2c);
        }
        for (long long k2 = (n4 << 2) + gtid; k2 < n; k2 += nthr) {
            dbin(img1[k2], h1c);
            dbin(img2[k2], h2c);
        }
    }

    // ---- flush: merge ballot counters into LDS copies, reduce, global ----
    __syncthreads();
#pragma unroll
    for (int j = 0; j < 4; ++j) {
        if (cnt1[j]) atomicAdd(&lh[0][4 * lane + j][copy], cnt1[j]);
        if (cnt2[j]) atomicAdd(&lh[1][4 * lane + j][copy], cnt2[j]);
    }
    __syncthreads();

    for (int b = tid; b < BINS; b += BLOCK) {
        u32 s1 = 0u, s2 = 0u;
#pragma unroll
        for (int c = 0; c < NCOPY; ++c) { s1 += lh[0][b][c]; s2 += lh[1][b][c]; }
        if (s1) atomicAdd(&g_h1[b], s1);
        if (s2) atomicAdd(&g_h2[b], s2);
    }
}

// Pass 2: fold global copies + loss = sum |c1/N1 - c2/N2| / 256, double precision.
__global__ __launch_bounds__(BINS) void finalize_kernel(
    const u32* __restrict__ h1, const u32* __restrict__ h2,
    const u32* __restrict__ gcop, int g_on,
    float* __restrict__ out)
{
    const int tid = threadIdx.x;          // one thread per bin
    u32 c1 = h1[tid];
    u32 c2 = h2[tid];
    if (g_on) {
#pragma unroll 8
        for (int c = 0; c < GCOPY; ++c) {
            c1 += gcop[c * 512 + tid];
            c2 += gcop[c * 512 + 256 + tid];
        }
    }

    __shared__ u32 s1[4], s2[4];
    __shared__ double sd[4];

    u32 r1 = c1, r2 = c2;
#pragma unroll
    for (int off = 32; off > 0; off >>= 1) {
        r1 += __shfl_down(r1, off);
        r2 += __shfl_down(r2, off);
    }
    if ((tid & 63) == 0) { s1[tid >> 6] = r1; s2[tid >> 6] = r2; }
    __syncthreads();

    const double N1 = (double)(s1[0] + s1[1] + s1[2] + s1[3]);
    const double N2 = (double)(s2[0] + s2[1] + s2[2] + s2[3]);

    double d = fabs((double)c1 / N1 - (double)c2 / N2);
#pragma unroll
    for (int off = 32; off > 0; off >>= 1)
        d += __shfl_down(d, off);
    if ((tid & 63) == 0) sd[tid >> 6] = d;
    __syncthreads();

    if (tid == 0) {
        double tot = sd[0] + sd[1] + sd[2] + sd[3];
        out[0] = (float)(tot / (double)BINS);
    }
}

extern "C" void kernel_launch(void* const* d_in, const int* in_sizes, int n_in,
                              void* d_out, int out_size, void* d_ws, size_t ws_size,
                              hipStream_t stream) {
    const float* img1 = (const float*)d_in[0];
    const float* img2 = (const float*)d_in[1];
    const long long n = (long long)in_sizes[0];

    u32* g_h1 = (u32*)d_ws;
    u32* g_h2 = g_h1 + BINS;
    u32* gcop = g_h2 + BINS;

    const size_t need = (size_t)(2 * BINS + GCOPY * 512) * sizeof(u32);
    const int g_on = (ws_size >= need) ? 1 : 0;

    hipMemsetAsync(d_ws, 0, g_on ? need : 2 * BINS * sizeof(u32), stream);

    hist_kernel<<<GRID, BLOCK, 0, stream>>>(img1, img2, g_h1, g_h2, gcop, g_on, n);
    finalize_kernel<<<1, BINS, 0, stream>>>(g_h1, g_h2, gcop, g_on, (float*)d_out);
}

// Round 13
// 54.612 us; speedup vs baseline: 4.3595x; 4.3595x over previous
//
#include <hip/hip_runtime.h>

#define BINS  256
#define NCOPY 8
#define BLOCK 512      // 8 waves: wid 0-3 ballot (one per SIMD), wid 4-7 DS (one per SIMD)
#define HALFT 256      // threads per role per block
#define GRID  1024     // 4 blocks/CU exactly (32 waves/CU); tripsTot = 24 for this shape

typedef unsigned int u32;
typedef unsigned long long u64;

// ---- rare fallback paths (exact semantics, global atomics) ----
__device__ __forceinline__ void gbin1(float x, u32* g) {
    if (x >= 0.0f && x <= 1.0f) {
        u32 bin = (u32)(x * 256.0f);     // trunc==floor for x>=0; matches JAX
        bin = bin > 255u ? 255u : bin;
        atomicAdd(&g[bin], 1u);
    }
}
__device__ __forceinline__ void gbin4(float4 v, u32* g) {
    gbin1(v.x, g); gbin1(v.y, g); gbin1(v.z, g); gbin1(v.w, g);
}

// ---- DS pipe: fire-and-forget LDS atomic (calibrated 640 G values/s chip-wide,
//      ~1 lane-op/cyc/CU, invariant to banking layout: R1/R3/R9) ----
__device__ __forceinline__ void dbin(float x, u32* hc) {
    if (x >= 0.0f && x <= 1.0f) {
        u32 bin = (u32)(x * 256.0f);
        bin = bin > 255u ? 255u : bin;
        atomicAdd(&hc[bin * NCOPY], 1u);
    }
}

// ---- ballot pipe: bit-slice count (calibrated ~390 G values/s; stall-limited) ----
// Lane owns bins 4*lane..4*lane+3 (bin bits 7:2 vs lane bits 5:0; bits 1:0 = j).
__device__ __forceinline__ void bs_round(float x, const u32 e[6], u32 cnt[4])
{
    u32 bin = (u32)(x * 256.0f);
    bin = bin > 255u ? 255u : bin;

    const u64 mv = __ballot(x >= 0.0f) & __ballot(x <= 1.0f);
    const u64 b0 = __ballot((bin & 1u) != 0u);
    const u64 b1 = __ballot((bin & 2u) != 0u);
    const u64 b2 = __ballot((bin & 4u) != 0u);
    const u64 b3 = __ballot((bin & 8u) != 0u);
    const u64 b4 = __ballot((bin & 16u) != 0u);
    const u64 b5 = __ballot((bin & 32u) != 0u);
    const u64 b6 = __ballot((bin & 64u) != 0u);
    const u64 b7 = __ballot((bin & 128u) != 0u);

    // per-lane fold in 32-bit halves: e[k] == (lane bit k) ? 0 : ~0
    u32 aLo = (u32)mv
            & (((u32)b2) ^ e[0]) & (((u32)b3) ^ e[1]) & (((u32)b4) ^ e[2])
            & (((u32)b5) ^ e[3]) & (((u32)b6) ^ e[4]) & (((u32)b7) ^ e[5]);
    u32 aHi = (u32)(mv >> 32)
            & (((u32)(b2 >> 32)) ^ e[0]) & (((u32)(b3 >> 32)) ^ e[1])
            & (((u32)(b4 >> 32)) ^ e[2]) & (((u32)(b5 >> 32)) ^ e[3])
            & (((u32)(b6 >> 32)) ^ e[4]) & (((u32)(b7 >> 32)) ^ e[5]);

    // wave-uniform low-bit combos (SALU), then per-lane and + popcount
    const u64 c00 = ~(b0 | b1);
    const u64 c01 = b0 & ~b1;
    const u64 c10 = ~b0 & b1;
    const u64 c11 = b0 & b1;
    cnt[0] += __popc(aLo & (u32)c00) + __popc(aHi & (u32)(c00 >> 32));
    cnt[1] += __popc(aLo & (u32)c01) + __popc(aHi & (u32)(c01 >> 32));
    cnt[2] += __popc(aLo & (u32)c10) + __popc(aHi & (u32)(c10 >> 32));
    cnt[3] += __popc(aLo & (u32)c11) + __popc(aHi & (u32)(c11 >> 32));
}

__device__ __forceinline__ void bs4(float4 v, const u32 e[6], u32 cnt[4])
{
    bs_round(v.x, e, cnt);
    bs_round(v.y, e, cnt);
    bs_round(v.z, e, cnt);
    bs_round(v.w, e, cnt);
}

// Wave-role specialized across all 4 SIMDs: waves 0-3 ballot, waves 4-7 DS.
// f = 9/24 = 0.375 ballot share, balanced to calibrated rates 390 : 640 G/s
// (f* = 390/1030 = 0.379). Both sides land at ~49 us: two-pipe roofline.
__global__ __launch_bounds__(BLOCK, 8) void hist_kernel(
    const float* __restrict__ img1, const float* __restrict__ img2,
    u32* __restrict__ g_h1, u32* __restrict__ g_h2,
    long long n)
{
    __shared__ u32 lh[2][BINS][NCOPY];       // 16 KB, bank-spread copies

    const int tid  = threadIdx.x;
    const int lane = tid & 63;
    const int copy = tid & (NCOPY - 1);

    for (int k = tid; k < 2 * BINS * NCOPY; k += BLOCK)
        ((u32*)lh)[k] = 0u;
    __syncthreads();

    u32 cnt1[4] = {0u, 0u, 0u, 0u};
    u32 cnt2[4] = {0u, 0u, 0u, 0u};
    u32* h1c = &lh[0][0][copy];
    u32* h2c = &lh[1][0][copy];

    const long long n4 = n >> 2;
    const long long S  = (long long)gridDim.x * HALFT;     // quads per role per trip
    const long long tripsTot = n4 / S;                     // 24 for this shape
    const long long tripsB = (tripsTot * 3) >> 3;          // ballot share f = 9/24
    const long long tripsD = tripsTot - tripsB;            // DS share 15/24
    const long long QB = tripsB * S;                       // ballot covers quads [0, QB)
    const long long uniform_end = QB + tripsD * S;         // == n4 when divisible

    const float4* p1 = (const float4*)img1;
    const float4* p2 = (const float4*)img2;

    if (tid < HALFT) {
        // ---- ballot role (waves 0-3, one per SIMD): pure VALU ----
        u32 e[6];
#pragma unroll
        for (int k = 0; k < 6; ++k)
            e[k] = ((lane >> k) & 1) ? 0u : 0xFFFFFFFFu;

        long long i = (long long)blockIdx.x * HALFT + tid;       // quads [0, QB)
        if (tripsB >= 2) {
            float4 a0 = p1[i],  b0 = p2[i];
            long long ii = i + S;
            float4 a1 = p1[ii], b1 = p2[ii];
            for (long long t = 0; t + 2 < tripsB; ++t) {
                const long long in = ii + S;
                float4 a2 = p1[in], b2v = p2[in];
                bs4(a0, e, cnt1); bs4(b0, e, cnt2);
                a0 = a1; b0 = b1; a1 = a2; b1 = b2v; ii = in;
            }
            bs4(a0, e, cnt1); bs4(b0, e, cnt2);
            bs4(a1, e, cnt1); bs4(b1, e, cnt2);
        } else if (tripsB == 1) {
            float4 a0 = p1[i], b0 = p2[i];
            bs4(a0, e, cnt1); bs4(b0, e, cnt2);
        }
    } else {
        // ---- DS role (waves 4-7, one per SIMD): fire-and-forget LDS atomics ----
        long long i = QB + (long long)blockIdx.x * HALFT + (tid - HALFT);  // quads [QB, n4)
        if (tripsD >= 2) {
            float4 a0 = p1[i],  b0 = p2[i];
            long long ii = i + S;
            float4 a1 = p1[ii], b1 = p2[ii];
            for (long long t = 0; t + 2 < tripsD; ++t) {
                const long long in = ii + S;
                float4 a2 = p1[in], b2v = p2[in];
                dbin(a0.x, h1c); dbin(a0.y, h1c); dbin(a0.z, h1c); dbin(a0.w, h1c);
                dbin(b0.x, h2c); dbin(b0.y, h2c); dbin(b0.z, h2c); dbin(b0.w, h2c);
                a0 = a1; b0 = b1; a1 = a2; b1 = b2v; ii = in;
            }
            dbin(a0.x, h1c); dbin(a0.y, h1c); dbin(a0.z, h1c); dbin(a0.w, h1c);
            dbin(b0.x, h2c); dbin(b0.y, h2c); dbin(b0.z, h2c); dbin(b0.w, h2c);
            dbin(a1.x, h1c); dbin(a1.y, h1c); dbin(a1.z, h1c); dbin(a1.w, h1c);
            dbin(b1.x, h2c); dbin(b1.y, h2c); dbin(b1.z, h2c); dbin(b1.w, h2c);
        } else if (tripsD == 1) {
            float4 a0 = p1[i], b0 = p2[i];
            dbin(a0.x, h1c); dbin(a0.y, h1c); dbin(a0.z, h1c); dbin(a0.w, h1c);
            dbin(b0.x, h2c); dbin(b0.y, h2c); dbin(b0.z, h2c); dbin(b0.w, h2c);
        }
    }

    // generic tails (empty for this shape)
    {
        const long long gtid = (long long)blockIdx.x * BLOCK + tid;
        const long long nthr = (long long)gridDim.x * BLOCK;
        for (long long q = uniform_end + gtid; q < n4; q += nthr) {
            gbin4(p1[q], g_h1);
            gbin4(p2[q], g_h2);
        }
        for (long long k2 = (n4 << 2) + gtid; k2 < n; k2 += nthr) {
            gbin1(img1[k2], g_h1);
            gbin1(img2[k2], g_h2);
        }
    }

    // ---- flush: merge ballot counters into LDS copies, reduce, global ----
    __syncthreads();                     // all DS-role atomics done
#pragma unroll
    for (int j = 0; j < 4; ++j) {        // DS threads have cnt==0, skip
        if (cnt1[j]) atomicAdd(&lh[0][4 * lane + j][copy], cnt1[j]);
        if (cnt2[j]) atomicAdd(&lh[1][4 * lane + j][copy], cnt2[j]);
    }
    __syncthreads();

    for (int b = tid; b < BINS; b += BLOCK) {
        u32 s1 = 0u, s2 = 0u;
#pragma unroll
        for (int c = 0; c < NCOPY; ++c) { s1 += lh[0][b][c]; s2 += lh[1][b][c]; }
        if (s1) atomicAdd(&g_h1[b], s1);
        if (s2) atomicAdd(&g_h2[b], s2);
    }
}

// Pass 2: loss = sum_i |c1[i]/N1 - c2[i]/N2| / 256, double precision.
__global__ __launch_bounds__(BINS) void finalize_kernel(
    const u32* __restrict__ h1, const u32* __restrict__ h2,
    float* __restrict__ out)
{
    const int tid = threadIdx.x;          // one thread per bin
    const u32 c1 = h1[tid];
    const u32 c2 = h2[tid];

    __shared__ u32 s1[4], s2[4];
    __shared__ double sd[4];

    u32 r1 = c1, r2 = c2;
#pragma unroll
    for (int off = 32; off > 0; off >>= 1) {
        r1 += __shfl_down(r1, off);
        r2 += __shfl_down(r2, off);
    }
    if ((tid & 63) == 0) { s1[tid >> 6] = r1; s2[tid >> 6] = r2; }
    __syncthreads();

    const double N1 = (double)(s1[0] + s1[1] + s1[2] + s1[3]);
    const double N2 = (double)(s2[0] + s2[1] + s2[2] + s2[3]);

    double d = fabs((double)c1 / N1 - (double)c2 / N2);
#pragma unroll
    for (int off = 32; off > 0; off >>= 1)
        d += __shfl_down(d, off);
    if ((tid & 63) == 0) sd[tid >> 6] = d;
    __syncthreads();

    if (tid == 0) {
        double tot = sd[0] + sd[1] + sd[2] + sd[3];
        out[0] = (float)(tot / (double)BINS);
    }
}

extern "C" void kernel_launch(void* const* d_in, const int* in_sizes, int n_in,
                              void* d_out, int out_size, void* d_ws, size_t ws_size,
                              hipStream_t stream) {
    const float* img1 = (const float*)d_in[0];
    const float* img2 = (const float*)d_in[1];
    const long long n = (long long)in_sizes[0];

    u32* g_h1 = (u32*)d_ws;
    u32* g_h2 = g_h1 + BINS;

    hipMemsetAsync(d_ws, 0, 2 * BINS * sizeof(u32), stream);

    hist_kernel<<<GRID, BLOCK, 0, stream>>>(img1, img2, g_h1, g_h2, n);
    finalize_kernel<<<1, BINS, 0, stream>>>(g_h1, g_h2, (float*)d_out);
}